// Round 1
// baseline (207.438 us; speedup 1.0000x reference)
//
#include <hip/hip_runtime.h>
#include <math.h>

#define Hs 64
#define Ws 64
#define HW 4096
#define CIN 256
#define DD 256
#define M_TOTAL 48

// ---------------------------------------------------------------------------
// K1: per-m flow (exact 4-px average of p_motions, x0.25 scale) + scatter of
// bilinear tap weights into A[m] (64x64), plus S[m] = sum(A[m]).
// ---------------------------------------------------------------------------
__global__ __launch_bounds__(256) void k_flow_scatter(
    const float* __restrict__ p_motions,
    float* __restrict__ Ag,      // [48][4096]
    float* __restrict__ Sg)      // [48]
{
    __shared__ float Al[HW];     // 16 KB
    __shared__ float red[4];
    const int m = blockIdx.x;
    const int tid = threadIdx.x;
    const float* p0 = p_motions + (size_t)m * 2 * 65536;  // dy channel
    const float* p1 = p0 + 65536;                         // dx channel

    for (int i = tid; i < HW; i += 256) Al[i] = 0.f;
    __syncthreads();

    for (int i = tid; i < HW; i += 256) {
        const int y = i >> 6, x = i & 63;
        const int r1 = 4 * y + 1, r2 = 4 * y + 2;
        const int c1 = 4 * x + 1, c2 = 4 * x + 2;
        // resize_bilinear degenerates to 0.5/0.5 weights at these taps
        float a = p0[r1 * 256 + c1], b = p0[r1 * 256 + c2];
        float c = p0[r2 * 256 + c1], d = p0[r2 * 256 + c2];
        float fy = ((a * 0.5f + b * 0.5f) * 0.5f + (c * 0.5f + d * 0.5f) * 0.5f) * 0.25f;
        a = p1[r1 * 256 + c1]; b = p1[r1 * 256 + c2];
        c = p1[r2 * 256 + c1]; d = p1[r2 * 256 + c2];
        float fx = ((a * 0.5f + b * 0.5f) * 0.5f + (c * 0.5f + d * 0.5f) * 0.5f) * 0.25f;

        const float yy = (float)y + fy;
        const float xx = (float)x + fx;
        const float y0f = floorf(yy), x0f = floorf(xx);
        const float wy = yy - y0f, wx = xx - x0f;
        const int iy0 = (int)y0f, ix0 = (int)x0f;
        const int iy1 = iy0 + 1, ix1 = ix0 + 1;
        const float w00 = (1.f - wy) * (1.f - wx);
        const float w01 = (1.f - wy) * wx;
        const float w10 = wy * (1.f - wx);
        const float w11 = wy * wx;
        const bool y0ok = (iy0 >= 0) & (iy0 < Hs);
        const bool y1ok = (iy1 >= 0) & (iy1 < Hs);
        const bool x0ok = (ix0 >= 0) & (ix0 < Ws);
        const bool x1ok = (ix1 >= 0) & (ix1 < Ws);
        if (y0ok & x0ok) atomicAdd(&Al[iy0 * Ws + ix0], w00);
        if (y0ok & x1ok) atomicAdd(&Al[iy0 * Ws + ix1], w01);
        if (y1ok & x0ok) atomicAdd(&Al[iy1 * Ws + ix0], w10);
        if (y1ok & x1ok) atomicAdd(&Al[iy1 * Ws + ix1], w11);
    }
    __syncthreads();

    float part = 0.f;
    for (int i = tid; i < HW; i += 256) {
        const float v = Al[i];
        Ag[(size_t)m * HW + i] = v;
        part += v;
    }
    for (int off = 32; off > 0; off >>= 1) part += __shfl_down(part, off, 64);
    const int wave = tid >> 6, lane = tid & 63;
    if (lane == 0) red[wave] = part;
    __syncthreads();
    if (tid == 0) Sg[m] = red[0] + red[1] + red[2] + red[3];
}

// ---------------------------------------------------------------------------
// K2: g[m,ci] = (1/4096) * sum_p A[m,p] * i_features[fm,ci,p]
// Grid: (fm=16, chunk=16); each block stages the 3 A maps of its fm in LDS
// and streams 16 channels of i_features once (float4, coalesced).
// ---------------------------------------------------------------------------
__global__ __launch_bounds__(256) void k_gather_dot(
    const float* __restrict__ i_features,
    const float* __restrict__ Ag,
    float* __restrict__ g)       // [48][256]
{
    __shared__ float Al[3][HW];  // 48 KB
    const int fm = blockIdx.x;    // 0..15
    const int chunk = blockIdx.y; // 0..15
    const int tid = threadIdx.x;
    const int b = fm >> 2, gg = fm & 3;
    const int m0 = b * 12 + gg * 3;

    for (int j = 0; j < 3; ++j) {
        const float4* src = (const float4*)(Ag + (size_t)(m0 + j) * HW);
        float4* dst = (float4*)Al[j];
        for (int i = tid; i < HW / 4; i += 256) dst[i] = src[i];
    }
    __syncthreads();

    const int wave = tid >> 6, lane = tid & 63;
    const float4* A0 = (const float4*)Al[0];
    const float4* A1 = (const float4*)Al[1];
    const float4* A2 = (const float4*)Al[2];

    for (int cl = wave; cl < 16; cl += 4) {
        const int ci = chunk * 16 + cl;
        const float4* f4 = (const float4*)(i_features + ((size_t)fm * CIN + ci) * HW);
        float s0 = 0.f, s1 = 0.f, s2 = 0.f;
        for (int k = lane; k < HW / 4; k += 64) {
            const float4 v = f4[k];
            const float4 a0 = A0[k], a1 = A1[k], a2 = A2[k];
            s0 += v.x * a0.x + v.y * a0.y + v.z * a0.z + v.w * a0.w;
            s1 += v.x * a1.x + v.y * a1.y + v.z * a1.z + v.w * a1.w;
            s2 += v.x * a2.x + v.y * a2.y + v.z * a2.z + v.w * a2.w;
        }
        for (int off = 32; off > 0; off >>= 1) {
            s0 += __shfl_down(s0, off, 64);
            s1 += __shfl_down(s1, off, 64);
            s2 += __shfl_down(s2, off, 64);
        }
        if (lane == 0) {
            const float inv = 1.f / 4096.f;
            g[(size_t)(m0 + 0) * CIN + ci] = s0 * inv;
            g[(size_t)(m0 + 1) * CIN + ci] = s1 * inv;
            g[(size_t)(m0 + 2) * CIN + ci] = s2 * inv;
        }
    }
}

// ---------------------------------------------------------------------------
// K3: out[m,o] = W_dc[o,:] @ (W_emb @ g[m] + b_emb * S[m]/4096) + b_dc[o]
// One block per m; two chained GEMVs through LDS.
// ---------------------------------------------------------------------------
__global__ __launch_bounds__(256) void k_out(
    const float* __restrict__ g,
    const float* __restrict__ Sg,
    const float* __restrict__ W_emb,
    const float* __restrict__ b_emb,
    const float* __restrict__ W_dc,
    const float* __restrict__ b_dc,
    float* __restrict__ out)
{
    __shared__ float gl[CIN];
    __shared__ float sm[DD];
    const int m = blockIdx.x;
    const int tid = threadIdx.x;

    gl[tid] = g[(size_t)m * CIN + tid];
    __syncthreads();

    const float Sm = Sg[m] * (1.f / 4096.f);
    float acc = 0.f;
    const float4* wr = (const float4*)(W_emb + (size_t)tid * CIN);
    for (int k = 0; k < CIN / 4; ++k) {
        const float4 wv = wr[k];
        acc += wv.x * gl[4 * k] + wv.y * gl[4 * k + 1] + wv.z * gl[4 * k + 2] + wv.w * gl[4 * k + 3];
    }
    sm[tid] = acc + b_emb[tid] * Sm;
    __syncthreads();

    float acc2 = 0.f;
    const float4* wr2 = (const float4*)(W_dc + (size_t)tid * CIN);
    for (int k = 0; k < CIN / 4; ++k) {
        const float4 wv = wr2[k];
        acc2 += wv.x * sm[4 * k] + wv.y * sm[4 * k + 1] + wv.z * sm[4 * k + 2] + wv.w * sm[4 * k + 3];
    }
    out[(size_t)m * DD + tid] = acc2 + b_dc[tid];
}

// ---------------------------------------------------------------------------
extern "C" void kernel_launch(void* const* d_in, const int* in_sizes, int n_in,
                              void* d_out, int out_size, void* d_ws, size_t ws_size,
                              hipStream_t stream) {
    // setup_inputs order: imgs, i_features, p_motions, W_emb, b_emb, W_dc, b_dc
    const float* i_features = (const float*)d_in[1];
    const float* p_motions  = (const float*)d_in[2];
    const float* W_emb      = (const float*)d_in[3];
    const float* b_emb      = (const float*)d_in[4];
    const float* W_dc       = (const float*)d_in[5];
    const float* b_dc       = (const float*)d_in[6];
    float* out = (float*)d_out;

    float* ws = (float*)d_ws;
    float* Ag = ws;                          // 48*4096 floats
    float* Sg = Ag + (size_t)M_TOTAL * HW;   // 48 floats (padded to 64)
    float* g  = Sg + 64;                     // 48*256 floats

    k_flow_scatter<<<M_TOTAL, 256, 0, stream>>>(p_motions, Ag, Sg);
    dim3 grid2(16, 16);
    k_gather_dot<<<grid2, 256, 0, stream>>>(i_features, Ag, g);
    k_out<<<M_TOTAL, 256, 0, stream>>>(g, Sg, W_emb, b_emb, W_dc, b_dc, out);
}

// Round 2
// 172.047 us; speedup vs baseline: 1.2057x; 1.2057x over previous
//
#include <hip/hip_runtime.h>
#include <math.h>

#define HW 4096
#define CIN 256
#define DD 256
#define M_TOTAL 48
#define NSP 4
#define SPPX (HW / NSP)   // 1024 pixels per spatial slice

// ---------------------------------------------------------------------------
// K1: flow (exact 4-px average of p_motions x 0.25) + scatter of bilinear tap
// weights. Grid (m=48, sp=4): each block scatters its quarter's taps into a
// private LDS 64x64 map, then skip-zero atomicAdd into global Ag[m].
// Ag/Sg must be pre-zeroed (hipMemsetAsync in kernel_launch).
// ---------------------------------------------------------------------------
__global__ __launch_bounds__(256) void k_flow_scatter(
    const float* __restrict__ p_motions,
    float* __restrict__ Ag,      // [48][4096]
    float* __restrict__ Sg)      // [48]
{
    __shared__ float Al[HW];     // 16 KB, block-private partial map
    __shared__ float red[4];
    const int m = blockIdx.x;
    const int sp = blockIdx.y;
    const int tid = threadIdx.x;
    const float* p0 = p_motions + (size_t)m * 2 * 65536;  // dy channel
    const float* p1 = p0 + 65536;                         // dx channel

    for (int i = tid; i < HW; i += 256) Al[i] = 0.f;
    __syncthreads();

    for (int ii = tid; ii < SPPX; ii += 256) {
        const int i = sp * SPPX + ii;
        const int y = i >> 6, x = i & 63;
        const int r1 = 4 * y + 1, r2 = 4 * y + 2;
        const int c1 = 4 * x + 1, c2 = 4 * x + 2;
        // resize_bilinear degenerates to 0.5/0.5 weights at these taps
        float a = p0[r1 * 256 + c1], b = p0[r1 * 256 + c2];
        float c = p0[r2 * 256 + c1], d = p0[r2 * 256 + c2];
        float fy = ((a * 0.5f + b * 0.5f) * 0.5f + (c * 0.5f + d * 0.5f) * 0.5f) * 0.25f;
        a = p1[r1 * 256 + c1]; b = p1[r1 * 256 + c2];
        c = p1[r2 * 256 + c1]; d = p1[r2 * 256 + c2];
        float fx = ((a * 0.5f + b * 0.5f) * 0.5f + (c * 0.5f + d * 0.5f) * 0.5f) * 0.25f;

        const float yy = (float)y + fy;
        const float xx = (float)x + fx;
        const float y0f = floorf(yy), x0f = floorf(xx);
        const float wy = yy - y0f, wx = xx - x0f;
        const int iy0 = (int)y0f, ix0 = (int)x0f;
        const int iy1 = iy0 + 1, ix1 = ix0 + 1;
        const float w00 = (1.f - wy) * (1.f - wx);
        const float w01 = (1.f - wy) * wx;
        const float w10 = wy * (1.f - wx);
        const float w11 = wy * wx;
        const bool y0ok = (iy0 >= 0) & (iy0 < 64);
        const bool y1ok = (iy1 >= 0) & (iy1 < 64);
        const bool x0ok = (ix0 >= 0) & (ix0 < 64);
        const bool x1ok = (ix1 >= 0) & (ix1 < 64);
        if (y0ok & x0ok) atomicAdd(&Al[iy0 * 64 + ix0], w00);
        if (y0ok & x1ok) atomicAdd(&Al[iy0 * 64 + ix1], w01);
        if (y1ok & x0ok) atomicAdd(&Al[iy1 * 64 + ix0], w10);
        if (y1ok & x1ok) atomicAdd(&Al[iy1 * 64 + ix1], w11);
    }
    __syncthreads();

    float part = 0.f;
    float* AgM = Ag + (size_t)m * HW;
    for (int i = tid; i < HW; i += 256) {
        const float v = Al[i];
        part += v;
        if (v != 0.f) atomicAdd(&AgM[i], v);  // skip-zero: most of map untouched
    }
    for (int off = 32; off > 0; off >>= 1) part += __shfl_down(part, off, 64);
    const int wave = tid >> 6, lane = tid & 63;
    if (lane == 0) red[wave] = part;
    __syncthreads();
    if (tid == 0) atomicAdd(&Sg[m], red[0] + red[1] + red[2] + red[3]);
}

// ---------------------------------------------------------------------------
// K2: fold the two 1x1 convs: WT[ci][o] = sum_k W_dc[o,k]*W_emb[k,ci]
// (stored TRANSPOSED so k_out's GEMV reads are lane-coalesced), and
// bfold[o] = sum_k W_dc[o,k]*b_emb[k].
// ---------------------------------------------------------------------------
__global__ __launch_bounds__(256) void k_fold(
    const float* __restrict__ W_emb,
    const float* __restrict__ b_emb,
    const float* __restrict__ W_dc,
    float* __restrict__ WT,      // [256][256] = WT[ci*256+o]
    float* __restrict__ bfold)   // [256]
{
    __shared__ float wdc[256];
    __shared__ float red[4];
    const int o = blockIdx.x, tid = threadIdx.x;
    wdc[tid] = W_dc[(size_t)o * 256 + tid];
    __syncthreads();
    float acc = 0.f;
    #pragma unroll 8
    for (int k = 0; k < 256; ++k)
        acc += wdc[k] * W_emb[(size_t)k * 256 + tid];   // coalesced row reads
    WT[(size_t)tid * 256 + o] = acc;                    // transposed store

    float pb = wdc[tid] * b_emb[tid];
    for (int off = 32; off > 0; off >>= 1) pb += __shfl_down(pb, off, 64);
    if ((tid & 63) == 0) red[tid >> 6] = pb;
    __syncthreads();
    if (tid == 0) bfold[o] = red[0] + red[1] + red[2] + red[3];
}

// ---------------------------------------------------------------------------
// K3: gpart[sp][m][ci] = sum_{p in slice sp} A[m,p] * i_features[fm,ci,p]
// Grid (fm=16, chunk=16, sp=4) = 1024 blocks, 12 KB LDS -> ~16 waves/CU.
// ---------------------------------------------------------------------------
__global__ __launch_bounds__(256) void k_gather_dot(
    const float* __restrict__ i_features,
    const float* __restrict__ Ag,
    float* __restrict__ gpart)   // [NSP][48][256]
{
    __shared__ float Al[3][SPPX];  // 12 KB
    const int fm = blockIdx.x;     // 0..15
    const int chunk = blockIdx.y;  // 0..15
    const int sp = blockIdx.z;     // 0..3
    const int tid = threadIdx.x;
    const int m0 = fm * 3;

    // stage: 3 maps x 256 float4 -> exactly one float4 per thread per map
    {
        const float4* s0 = (const float4*)(Ag + (size_t)(m0 + 0) * HW + sp * SPPX);
        const float4* s1 = (const float4*)(Ag + (size_t)(m0 + 1) * HW + sp * SPPX);
        const float4* s2 = (const float4*)(Ag + (size_t)(m0 + 2) * HW + sp * SPPX);
        ((float4*)Al[0])[tid] = s0[tid];
        ((float4*)Al[1])[tid] = s1[tid];
        ((float4*)Al[2])[tid] = s2[tid];
    }
    __syncthreads();

    const int wave = tid >> 6, lane = tid & 63;
    const float4* A0 = (const float4*)Al[0];
    const float4* A1 = (const float4*)Al[1];
    const float4* A2 = (const float4*)Al[2];

    for (int cl = wave; cl < 16; cl += 4) {
        const int ci = chunk * 16 + cl;
        const float4* f4 = (const float4*)(i_features + ((size_t)fm * CIN + ci) * HW + sp * SPPX);
        float s0 = 0.f, s1 = 0.f, s2 = 0.f;
        #pragma unroll
        for (int k = lane; k < SPPX / 4; k += 64) {
            const float4 v = f4[k];
            const float4 a0 = A0[k], a1 = A1[k], a2 = A2[k];
            s0 += v.x * a0.x + v.y * a0.y + v.z * a0.z + v.w * a0.w;
            s1 += v.x * a1.x + v.y * a1.y + v.z * a1.z + v.w * a1.w;
            s2 += v.x * a2.x + v.y * a2.y + v.z * a2.z + v.w * a2.w;
        }
        for (int off = 32; off > 0; off >>= 1) {
            s0 += __shfl_down(s0, off, 64);
            s1 += __shfl_down(s1, off, 64);
            s2 += __shfl_down(s2, off, 64);
        }
        if (lane == 0) {
            gpart[((size_t)sp * M_TOTAL + m0 + 0) * CIN + ci] = s0;
            gpart[((size_t)sp * M_TOTAL + m0 + 1) * CIN + ci] = s1;
            gpart[((size_t)sp * M_TOTAL + m0 + 2) * CIN + ci] = s2;
        }
    }
}

// ---------------------------------------------------------------------------
// K4: out[m,o] = sum_ci WT[ci,o]*g[m,ci] + bfold[o]*S[m]/4096 + b_dc[o]
// WT reads are lane-coalesced (o contiguous); gl[ci] is an LDS broadcast.
// ---------------------------------------------------------------------------
__global__ __launch_bounds__(256) void k_out(
    const float* __restrict__ gpart,
    const float* __restrict__ Sg,
    const float* __restrict__ WT,
    const float* __restrict__ bfold,
    const float* __restrict__ b_dc,
    float* __restrict__ out)
{
    __shared__ float gl[CIN];
    const int m = blockIdx.x;
    const int tid = threadIdx.x;

    float gv = 0.f;
    for (int sp = 0; sp < NSP; ++sp)
        gv += gpart[((size_t)sp * M_TOTAL + m) * CIN + tid];
    gl[tid] = gv * (1.f / 4096.f);
    __syncthreads();

    const float Sm = Sg[m] * (1.f / 4096.f);
    float acc = 0.f;
    #pragma unroll 8
    for (int ci = 0; ci < CIN; ++ci)
        acc += gl[ci] * WT[(size_t)ci * DD + tid];   // coalesced across lanes
    out[(size_t)m * DD + tid] = acc + bfold[tid] * Sm + b_dc[tid];
}

// ---------------------------------------------------------------------------
extern "C" void kernel_launch(void* const* d_in, const int* in_sizes, int n_in,
                              void* d_out, int out_size, void* d_ws, size_t ws_size,
                              hipStream_t stream) {
    // setup_inputs order: imgs, i_features, p_motions, W_emb, b_emb, W_dc, b_dc
    const float* i_features = (const float*)d_in[1];
    const float* p_motions  = (const float*)d_in[2];
    const float* W_emb      = (const float*)d_in[3];
    const float* b_emb      = (const float*)d_in[4];
    const float* W_dc       = (const float*)d_in[5];
    const float* b_dc       = (const float*)d_in[6];
    float* out = (float*)d_out;

    float* ws = (float*)d_ws;
    float* Ag    = ws;                                // 48*4096
    float* Sg    = Ag + (size_t)M_TOTAL * HW;         // 64 (48 used)
    float* WT    = Sg + 64;                           // 65536
    float* bfold = WT + 65536;                        // 256
    float* gpart = bfold + 256;                       // 4*48*256
    // total ~311616 floats ~1.19 MB

    hipMemsetAsync(Ag, 0, ((size_t)M_TOTAL * HW + 64) * sizeof(float), stream);

    dim3 g1(M_TOTAL, NSP);
    k_flow_scatter<<<g1, 256, 0, stream>>>(p_motions, Ag, Sg);
    k_fold<<<DD, 256, 0, stream>>>(W_emb, b_emb, W_dc, WT, bfold);
    dim3 g3(16, 16, NSP);
    k_gather_dot<<<g3, 256, 0, stream>>>(i_features, Ag, gpart);
    k_out<<<M_TOTAL, 256, 0, stream>>>(gpart, Sg, WT, bfold, b_dc, out);
}